// Round 13
// baseline (119.386 us; speedup 1.0000x reference)
//
#include <hip/hip_runtime.h>

// Problem constants
#define B_DIM   4096
#define C_DIM   128
#define P_IDS   256          // B/K_INST
#define INV_TEMP 20.0f       // 1/0.05
#define EPS 1e-6f

#define A_CHUNKS 65536       // 4096*128/8  (bf16x8 chunks)

typedef unsigned short u16;
typedef __attribute__((ext_vector_type(8))) short bf16x8;
typedef __attribute__((ext_vector_type(4))) float f32x4;

__device__ __forceinline__ u16 f2bf(float x) {
    union { float f; unsigned u; } v; v.f = x;
    unsigned r = v.u + 0x7fffu + ((v.u >> 16) & 1u);   // RTN-even
    return (u16)(r >> 16);
}

// ---------------- kernel 1: fp32 -> bf16 fragment-tiled A (A only, 1 MB out) ----------------
// Chunk c (16B = 8 bf16): grow=c>>8, kk=(c>>6)&3, lane=c&63, g=lane>>4,
// r=lane&15 -> holds feats[grow*16 + r][kk*32 + g*8 .. +8].
__global__ __launch_bounds__(256) void convert_bf16(const float* __restrict__ feats,
                                                    u16* __restrict__ A_t) {
    const int c = blockIdx.x * 256 + threadIdx.x;       // 65536 chunks
    const int grow = c >> 8, kk = (c >> 6) & 3, lane = c & 63;
    const int g = lane >> 4, r = lane & 15;
    const float* src = feats + (size_t)(grow * 16 + r) * C_DIM + kk * 32 + g * 8;
    float4 u0 = *(const float4*)src;
    float4 u1 = *(const float4*)(src + 4);
    bf16x8 o;
    o[0] = (short)f2bf(u0.x); o[1] = (short)f2bf(u0.y);
    o[2] = (short)f2bf(u0.z); o[3] = (short)f2bf(u0.w);
    o[4] = (short)f2bf(u1.x); o[5] = (short)f2bf(u1.y);
    o[6] = (short)f2bf(u1.z); o[7] = (short)f2bf(u1.w);
    *(bf16x8*)(A_t + (size_t)c * 8) = o;
}

// ---------------- kernel 2: zero-LDS streaming sim + max/min ----------------
// R19 = R12 structure (109.6 best) + B-from-fp32 prologue (R13) + opacity
// barrier (R14). Ledger after 8 probes: phase1 ~40 us under EVERY structure;
// TLP/depth/B-handling/shape/A-dedup/epilogue-rotation (R18: -4.7, reverted)
// all exonerated. Remaining measurable waste = the serial chain: convert was
// moving 27 MB (~4.4 us) just to pre-tile B.
//  * convert is A-only (3 MB, ~0.7 us). B fragments built in-register from
//    fp32 feats_s ONCE per block (32 float4 loads + 384 cvt, amortized over
//    32 steps), then OPACITY-PINNED: R13's per-step remat is impossible
//    (R14-proven mechanism). Validation: if phase1 >= 48 us w/ VGPR ~80,
//    remat returned -> revert to R12.
//  * Everything else byte-identical to R12: (256,2), depth-1 prefetch,
//    zero LDS / zero barriers, swapped MFMA operands, [wn][p][row] pmax
//    (exclusive 64B-line stores), balanced-tree epilogue.
__global__ __launch_bounds__(256, 2) void phase1(const u16*  __restrict__ A_t,   // frag-tiled bf16 A
                                                 const float* __restrict__ Bm32, // fp32 [32768][128]
                                                 float* __restrict__ pmax,       // [2][256][4096]
                                                 float* __restrict__ pmin)       // [2][4096]
{
    const int tid  = threadIdx.x;
    const int lane = tid & 63;
    const int wave = tid >> 6;
    const int wm   = wave >> 1;       // row half of block's 1024 rows
    const int wn   = wave & 1;        // col half (64 of 128 support cols)
    const int p    = blockIdx.x;      // identity 0..255
    const int h    = blockIdx.y;      // row quarter: rows h*1024..+1023
    const int r    = lane & 15;
    const int g    = lane >> 4;

    // ---- B fragments: fp32 -> bf16 in-register (one-time), then OPAQUE ----
    // b[ni][kk] holds B[p*128 + wn*64 + ni*16 + r][kk*32 + g*8 .. +8]
    bf16x8 b[4][4];
    {
        const float* brow = Bm32 + (size_t)(p * 128 + wn * 64 + r) * C_DIM + g * 8;
#pragma unroll
        for (int ni = 0; ni < 4; ++ni)
#pragma unroll
            for (int kk = 0; kk < 4; ++kk) {
                const float* s0 = brow + (size_t)ni * 16 * C_DIM + kk * 32;
                float4 u0 = *(const float4*)s0;
                float4 u1 = *(const float4*)(s0 + 4);
                bf16x8 f;
                f[0] = (short)f2bf(u0.x); f[1] = (short)f2bf(u0.y);
                f[2] = (short)f2bf(u0.z); f[3] = (short)f2bf(u0.w);
                f[4] = (short)f2bf(u1.x); f[5] = (short)f2bf(u1.y);
                f[6] = (short)f2bf(u1.z); f[7] = (short)f2bf(u1.w);
                b[ni][kk] = f;
            }
    }
    // Opacity barrier: origin unknowable -> per-step rematerialization (the
    // R13 failure: re-load fp32 + re-run cvt chain every step) is impossible.
#pragma unroll
    for (int ni = 0; ni < 4; ++ni)
#pragma unroll
        for (int kk = 0; kk < 4; ++kk)
            asm volatile("" : "+v"(b[ni][kk]));

    // ---- A stream addressing: 32 steps of 16 rows ----
    const int grow0 = h * 64 + wm * 32;                        // global row-group base
    const u16* abase = A_t + ((size_t)grow0 * 256 + lane) * 8; // +s*2048, +kk*512 (u16)

    // pmax [wn][p][row]: this wave owns rows h*1024 + wm*512 .. +511 at (wn,p)
    float* const pq = pmax + ((size_t)wn * P_IDS + p) * B_DIM + h * 1024 + wm * 512;
    const bool dhit = (h == (p >> 6)) && (wm == ((p >> 5) & 1));
    const int  ssel = p & 31;

#define LOADA(dst, ss) do { const u16* ap = abase + (size_t)(ss) * 2048;         \
        dst[0] = *(const bf16x8*)ap;         dst[1] = *(const bf16x8*)(ap + 512); \
        dst[2] = *(const bf16x8*)(ap + 1024); dst[3] = *(const bf16x8*)(ap + 1536); } while (0)

    // D[n][m] per lane (operands swapped): col(lane&15)=A-row, row(g*4+rr)=B-col
#define STEP(areg, ss) do {                                                       \
        f32x4 acc[4] = {};                                                        \
        _Pragma("unroll")                                                         \
        for (int kk = 0; kk < 4; ++kk) {                                          \
            _Pragma("unroll")                                                     \
            for (int ni = 0; ni < 4; ++ni)                                        \
                acc[ni] = __builtin_amdgcn_mfma_f32_16x16x32_bf16(                \
                    b[ni][kk], areg[kk], acc[ni], 0, 0, 0);                       \
        }                                                                         \
        float t0 = fmaxf(fmaxf(acc[0][0], acc[0][1]), fmaxf(acc[0][2], acc[0][3]));\
        float t1 = fmaxf(fmaxf(acc[1][0], acc[1][1]), fmaxf(acc[1][2], acc[1][3]));\
        float t2 = fmaxf(fmaxf(acc[2][0], acc[2][1]), fmaxf(acc[2][2], acc[2][3]));\
        float t3 = fmaxf(fmaxf(acc[3][0], acc[3][1]), fmaxf(acc[3][2], acc[3][3]));\
        float mx = fmaxf(fmaxf(t0, t1), fmaxf(t2, t3));                           \
        mx = fmaxf(mx, __shfl_xor(mx, 16, 64));                                   \
        mx = fmaxf(mx, __shfl_xor(mx, 32, 64));                                   \
        if (lane < 16) pq[(ss) * 16 + lane] = mx;                                 \
        if (dhit && (ss) == ssel) {                                               \
            float n0 = fminf(fminf(acc[0][0], acc[0][1]), fminf(acc[0][2], acc[0][3]));\
            float n1 = fminf(fminf(acc[1][0], acc[1][1]), fminf(acc[1][2], acc[1][3]));\
            float n2 = fminf(fminf(acc[2][0], acc[2][1]), fminf(acc[2][2], acc[2][3]));\
            float n3 = fminf(fminf(acc[3][0], acc[3][1]), fminf(acc[3][2], acc[3][3]));\
            float mn = fminf(fminf(n0, n1), fminf(n2, n3));                       \
            mn = fminf(mn, __shfl_xor(mn, 16, 64));                               \
            mn = fminf(mn, __shfl_xor(mn, 32, 64));                               \
            if (lane < 16) pmin[wn * B_DIM + p * 16 + lane] = mn;                 \
        }                                                                         \
    } while (0)

    bf16x8 aA[4], aB[4];
    LOADA(aA, 0);
#pragma unroll 1
    for (int s = 0; s < 32; s += 2) {
        LOADA(aB, s + 1);             // prefetch odd step
        STEP(aA, s);
        if (s + 2 < 32) LOADA(aA, s + 2);  // prefetch next even step
        STEP(aB, s + 1);
    }
#undef LOADA
#undef STEP
}

// ---------------- kernel 3: per-row loss + mean (stripe-transposed reads) ----------------
// 64 blocks x 256 thr. Block owns a 64-row stripe; lane = row, wave owns a
// 64-wide p-range. Every pmax load is a coalesced 256B line (L2-resident).
__global__ __launch_bounds__(256) void phase2(const float* __restrict__ pmax,  // [2][256][4096]
                                              const float* __restrict__ pmin,  // [2][4096]
                                              const int* __restrict__ labels,
                                              float* __restrict__ out) {
    const int tid  = threadIdx.x;
    const int lane = tid & 63;
    const int wave = tid >> 6;
    const int row  = blockIdx.x * 64 + lane;
    const int pid  = labels[row];
    const float* q0 = pmax + (size_t)(wave * 64) * B_DIM + row;   // p = wave*64+j
    const float* q1 = q0 + (size_t)P_IDS * B_DIM;
    float s = 0.f;
#pragma unroll 8
    for (int j = 0; j < 64; ++j) {
        const int p  = wave * 64 + j;
        const float v = fmaxf(q0[(size_t)j * B_DIM], q1[(size_t)j * B_DIM]);
        s += (p == pid) ? 0.f : __expf(v * INV_TEMP);
    }
    __shared__ float part[4][64];
    part[wave][lane] = s;
    __syncthreads();
    if (wave == 0) {
        const float neg = part[0][lane] + part[1][lane] + part[2][lane] + part[3][lane];
        const float mn  = fminf(pmin[row], pmin[B_DIM + row]);
        const float pos = __expf(mn * INV_TEMP);
        float loss = -__logf(pos / (pos + neg + EPS) + EPS);
        loss += __shfl_xor(loss, 1, 64);
        loss += __shfl_xor(loss, 2, 64);
        loss += __shfl_xor(loss, 4, 64);
        loss += __shfl_xor(loss, 8, 64);
        loss += __shfl_xor(loss, 16, 64);
        loss += __shfl_xor(loss, 32, 64);
        if (lane == 0) atomicAdd(out, loss * (1.0f / (float)B_DIM));
    }
}

extern "C" void kernel_launch(void* const* d_in, const int* in_sizes, int n_in,
                              void* d_out, int out_size, void* d_ws, size_t ws_size,
                              hipStream_t stream) {
    const float* feats   = (const float*)d_in[0];   // [4096,128]
    const float* feats_s = (const float*)d_in[1];   // [4096,8,128] fp32
    const int*   labels  = (const int*)d_in[2];     // [4096]
    float* out = (float*)d_out;

    // workspace: A_t (1 MB) | pmax (8 MB) | pmin (32 KB)
    u16* A_t = (u16*)d_ws;
    float* pmax = (float*)((char*)d_ws + (1u << 20));
    float* pmin = pmax + (size_t)2 * P_IDS * B_DIM;

    hipMemsetAsync(d_out, 0, sizeof(float), stream);
    convert_bf16<<<A_CHUNKS / 256, 256, 0, stream>>>(feats, A_t);
    dim3 g1(P_IDS, 4);
    phase1<<<g1, 256, 0, stream>>>(A_t, feats_s, pmax, pmin);
    phase2<<<B_DIM / 64, 256, 0, stream>>>(pmax, pmin, labels, out);
}

// Round 14
// 110.184 us; speedup vs baseline: 1.0835x; 1.0835x over previous
//
#include <hip/hip_runtime.h>

// Problem constants
#define B_DIM   4096
#define C_DIM   128
#define P_IDS   256          // B/K_INST
#define INV_TEMP 20.0f       // 1/0.05
#define EPS 1e-6f

#define A_CHUNKS 65536       // 4096*128/8  (bf16x8 chunks)
#define B_CHUNKS 524288      // 32768*128/8
#define ALL_CHUNKS (A_CHUNKS + B_CHUNKS)

typedef unsigned short u16;
typedef __attribute__((ext_vector_type(8))) short bf16x8;
typedef __attribute__((ext_vector_type(4))) float f32x4;

__device__ __forceinline__ u16 f2bf(float x) {
    union { float f; unsigned u; } v; v.f = x;
    unsigned r = v.u + 0x7fffu + ((v.u >> 16) & 1u);   // RTN-even
    return (u16)(r >> 16);
}

// ---------------- kernel 1: fp32 -> bf16 fragment-tiled A and B ----------------
// Chunk c (16B = 8 bf16): grow=c2>>8, kk=(c2>>6)&3, lane=c2&63, g=lane>>4,
// r=lane&15 -> holds SRC[grow*16 + r][kk*32 + g*8 .. +8].
// Chunks 0..65535 = feats (A), 65536.. = feats_s (B). Boundary is block-aligned
// (65536/256 = 256), so the branch is block-uniform.
__global__ __launch_bounds__(256) void convert_bf16(const float* __restrict__ feats,
                                                    const float* __restrict__ feats_s,
                                                    u16* __restrict__ T) {
    const int c = blockIdx.x * 256 + threadIdx.x;
    const float* base; int c2;
    if (c < A_CHUNKS) { base = feats;   c2 = c; }
    else              { base = feats_s; c2 = c - A_CHUNKS; }
    const int grow = c2 >> 8, kk = (c2 >> 6) & 3, lane = c2 & 63;
    const int g = lane >> 4, r = lane & 15;
    const float* src = base + (size_t)(grow * 16 + r) * C_DIM + kk * 32 + g * 8;
    float4 u0 = *(const float4*)src;
    float4 u1 = *(const float4*)(src + 4);
    bf16x8 o;
    o[0] = (short)f2bf(u0.x); o[1] = (short)f2bf(u0.y);
    o[2] = (short)f2bf(u0.z); o[3] = (short)f2bf(u0.w);
    o[4] = (short)f2bf(u1.x); o[5] = (short)f2bf(u1.y);
    o[6] = (short)f2bf(u1.z); o[7] = (short)f2bf(u1.w);
    *(bf16x8*)(T + (size_t)c * 8) = o;
}

// ---------------- kernel 2: zero-LDS streaming sim + max/min ----------------
// FINAL (R20) = R12 exactly, the best measured variant (109.6 us).
// Session ledger (9 structural probes, all neutral/negative vs this):
//   R11 LDS B-staging       -> compiler remat from LDS, 16 ds_read/step
//   R13 B from fp32         -> remat re-ran 384-op cvt chain/step (VGPR=80)
//   R14 opacity-pinned b    -> neutral (111.6)
//   R15 32x32x16 MFMA       -> regression (116.5, reg pressure)
//   R16 depth-2 prefetch    -> neutral (112.1) — latency exonerated
//   R17 full-width waves    -> regression (126.5, b[8][4] reg catastrophe)
//   R18 dual-acc rotation   -> regression (114.3)
//   R19 opacity + fp32 B    -> regression (119.4): opacity stops RECOMPUTE,
//                              not SPILL; allocator spilled pinned b to scratch.
// Why THIS structure wins: B pre-tiled to bf16 fragment layout makes the
// compiler's b-"remat" a single cheap 16B global re-load (L2-hit) per use —
// effectively an optimal software pipeline with zero register pressure
// (VGPR=64). Zero LDS, zero barriers, streaming A global->reg double-buffered.
// phase1 ~40 us; remaining gap to the 16.6 us MFMA floor is not addressable
// at HIP level per the 9-probe ledger (harness fixed floor ~69 us dominates).
__global__ __launch_bounds__(256, 2) void phase1(const u16*  __restrict__ T,   // frag-tiled bf16: A then B
                                                 float* __restrict__ pmax,     // [2][256][4096]
                                                 float* __restrict__ pmin)     // [2][4096]
{
    const int tid  = threadIdx.x;
    const int lane = tid & 63;
    const int wave = tid >> 6;
    const int wm   = wave >> 1;       // row half of block's 1024 rows
    const int wn   = wave & 1;        // col half (64 of 128 support cols)
    const int p    = blockIdx.x;      // identity 0..255
    const int h    = blockIdx.y;      // row quarter: rows h*1024..+1023

    // ---- B fragments: 16 one-time global loads -> registers ----
    // chunk for (ni,kk) = ((p*8 + wn*4 + ni)*4 + kk)*64 + lane
    const u16* bbase = T + (size_t)A_CHUNKS * 8
                         + ((size_t)(p * 8 + wn * 4) * 256 + lane) * 8;
    bf16x8 b[4][4];                   // [ni][kk]
#pragma unroll
    for (int ni = 0; ni < 4; ++ni)
#pragma unroll
        for (int kk = 0; kk < 4; ++kk)
            b[ni][kk] = *(const bf16x8*)(bbase + ni * 2048 + kk * 512);

    // ---- A stream addressing: 32 steps of 16 rows ----
    const int grow0 = h * 64 + wm * 32;                      // global row-group base
    const u16* abase = T + ((size_t)grow0 * 256 + lane) * 8; // +s*2048, +kk*512 (u16)

    // pmax [wn][p][row]: this wave owns rows h*1024 + wm*512 .. +511 at (wn,p)
    float* const pq = pmax + ((size_t)wn * P_IDS + p) * B_DIM + h * 1024 + wm * 512;
    const bool dhit = (h == (p >> 6)) && (wm == ((p >> 5) & 1));
    const int  ssel = p & 31;

#define LOADA(dst, ss) do { const u16* ap = abase + (size_t)(ss) * 2048;         \
        dst[0] = *(const bf16x8*)ap;         dst[1] = *(const bf16x8*)(ap + 512); \
        dst[2] = *(const bf16x8*)(ap + 1024); dst[3] = *(const bf16x8*)(ap + 1536); } while (0)

    // D[n][m] per lane (operands swapped): col(lane&15)=A-row, row(g*4+rr)=B-col
#define STEP(areg, ss) do {                                                       \
        f32x4 acc[4] = {};                                                        \
        _Pragma("unroll")                                                         \
        for (int kk = 0; kk < 4; ++kk) {                                          \
            _Pragma("unroll")                                                     \
            for (int ni = 0; ni < 4; ++ni)                                        \
                acc[ni] = __builtin_amdgcn_mfma_f32_16x16x32_bf16(                \
                    b[ni][kk], areg[kk], acc[ni], 0, 0, 0);                       \
        }                                                                         \
        float t0 = fmaxf(fmaxf(acc[0][0], acc[0][1]), fmaxf(acc[0][2], acc[0][3]));\
        float t1 = fmaxf(fmaxf(acc[1][0], acc[1][1]), fmaxf(acc[1][2], acc[1][3]));\
        float t2 = fmaxf(fmaxf(acc[2][0], acc[2][1]), fmaxf(acc[2][2], acc[2][3]));\
        float t3 = fmaxf(fmaxf(acc[3][0], acc[3][1]), fmaxf(acc[3][2], acc[3][3]));\
        float mx = fmaxf(fmaxf(t0, t1), fmaxf(t2, t3));                           \
        mx = fmaxf(mx, __shfl_xor(mx, 16, 64));                                   \
        mx = fmaxf(mx, __shfl_xor(mx, 32, 64));                                   \
        if (lane < 16) pq[(ss) * 16 + lane] = mx;                                 \
        if (dhit && (ss) == ssel) {                                               \
            float n0 = fminf(fminf(acc[0][0], acc[0][1]), fminf(acc[0][2], acc[0][3]));\
            float n1 = fminf(fminf(acc[1][0], acc[1][1]), fminf(acc[1][2], acc[1][3]));\
            float n2 = fminf(fminf(acc[2][0], acc[2][1]), fminf(acc[2][2], acc[2][3]));\
            float n3 = fminf(fminf(acc[3][0], acc[3][1]), fminf(acc[3][2], acc[3][3]));\
            float mn = fminf(fminf(n0, n1), fminf(n2, n3));                       \
            mn = fminf(mn, __shfl_xor(mn, 16, 64));                               \
            mn = fminf(mn, __shfl_xor(mn, 32, 64));                               \
            if (lane < 16) pmin[wn * B_DIM + p * 16 + lane] = mn;                 \
        }                                                                         \
    } while (0)

    bf16x8 aA[4], aB[4];
    LOADA(aA, 0);
#pragma unroll 1
    for (int s = 0; s < 32; s += 2) {
        LOADA(aB, s + 1);             // prefetch odd step
        STEP(aA, s);
        if (s + 2 < 32) LOADA(aA, s + 2);  // prefetch next even step
        STEP(aB, s + 1);
    }
#undef LOADA
#undef STEP
}

// ---------------- kernel 3: per-row loss + mean (stripe-transposed reads) ----------------
// 64 blocks x 256 thr. Block owns a 64-row stripe; lane = row, wave owns a
// 64-wide p-range. Every pmax load is a coalesced 256B line (L2-resident).
__global__ __launch_bounds__(256) void phase2(const float* __restrict__ pmax,  // [2][256][4096]
                                              const float* __restrict__ pmin,  // [2][4096]
                                              const int* __restrict__ labels,
                                              float* __restrict__ out) {
    const int tid  = threadIdx.x;
    const int lane = tid & 63;
    const int wave = tid >> 6;
    const int row  = blockIdx.x * 64 + lane;
    const int pid  = labels[row];
    const float* q0 = pmax + (size_t)(wave * 64) * B_DIM + row;   // p = wave*64+j
    const float* q1 = q0 + (size_t)P_IDS * B_DIM;
    float s = 0.f;
#pragma unroll 8
    for (int j = 0; j < 64; ++j) {
        const int p  = wave * 64 + j;
        const float v = fmaxf(q0[(size_t)j * B_DIM], q1[(size_t)j * B_DIM]);
        s += (p == pid) ? 0.f : __expf(v * INV_TEMP);
    }
    __shared__ float part[4][64];
    part[wave][lane] = s;
    __syncthreads();
    if (wave == 0) {
        const float neg = part[0][lane] + part[1][lane] + part[2][lane] + part[3][lane];
        const float mn  = fminf(pmin[row], pmin[B_DIM + row]);
        const float pos = __expf(mn * INV_TEMP);
        float loss = -__logf(pos / (pos + neg + EPS) + EPS);
        loss += __shfl_xor(loss, 1, 64);
        loss += __shfl_xor(loss, 2, 64);
        loss += __shfl_xor(loss, 4, 64);
        loss += __shfl_xor(loss, 8, 64);
        loss += __shfl_xor(loss, 16, 64);
        loss += __shfl_xor(loss, 32, 64);
        if (lane == 0) atomicAdd(out, loss * (1.0f / (float)B_DIM));
    }
}

extern "C" void kernel_launch(void* const* d_in, const int* in_sizes, int n_in,
                              void* d_out, int out_size, void* d_ws, size_t ws_size,
                              hipStream_t stream) {
    const float* feats   = (const float*)d_in[0];   // [4096,128]
    const float* feats_s = (const float*)d_in[1];   // [4096,8,128] fp32
    const int*   labels  = (const int*)d_in[2];     // [4096]
    float* out = (float*)d_out;

    // workspace: T = frag-tiled bf16 A(1 MB)+B(8 MB) | pmax (8 MB) | pmin (32 KB)
    u16* T = (u16*)d_ws;
    float* pmax = (float*)((char*)d_ws + (16u << 20));
    float* pmin = pmax + (size_t)2 * P_IDS * B_DIM;

    hipMemsetAsync(d_out, 0, sizeof(float), stream);
    convert_bf16<<<ALL_CHUNKS / 256, 256, 0, stream>>>(feats, feats_s, T);
    dim3 g1(P_IDS, 4);
    phase1<<<g1, 256, 0, stream>>>(T, pmax, pmin);
    phase2<<<B_DIM / 64, 256, 0, stream>>>(pmax, pmin, labels, out);
}